// Round 7
// baseline (1099.621 us; speedup 1.0000x reference)
//
#include <hip/hip_runtime.h>
#include <hip/hip_bf16.h>

typedef _Float16 f16;
typedef f16 v8h __attribute__((ext_vector_type(8)));
typedef float v4f __attribute__((ext_vector_type(4)));
typedef unsigned int v2u __attribute__((ext_vector_type(2)));
typedef unsigned short u16;
typedef unsigned int u32;

__device__ __forceinline__ u16 f2h(float f) {
  f16 h = (f16)f;
  return __builtin_bit_cast(unsigned short, h);
}
__device__ __forceinline__ float h2f(u16 u) {
  f16 h = __builtin_bit_cast(f16, u);
  return (float)h;
}
__device__ __forceinline__ u32 pk2(float a, float b) {
  return (u32)f2h(a) | ((u32)f2h(b) << 16);
}
#define MFMA16(a, b, c) __builtin_amdgcn_mfma_f32_16x16x32_f16((a), (b), (c), 0, 0, 0)

// ---------------- weight prep: fp32 row-major -> fp16 transposed/padded ----------------
// ws layout (u16 element offsets):
//   WcT  [64][128]  @ 0        (from W_cast 100x50,  zero-pad n>=50, k>=100)
//   Wa0T [256][64]  @ 8192     (from W_a0  50x256,   zero-pad k>=50)
//   Wa1T [400][256] @ 24576    (from W_a1  256x400)
//   Wp0T [256][416] @ 126976   (from W_p0  400x256,  zero-pad k>=400)
//   Wp1T [256][256] @ 233472   (from W_p1  256x256)
//   Wp2T [16][256]  @ 299008   (from W_p2  256x8,    zero-pad n>=8)
__global__ void prep_weights(const float* __restrict__ Wc, const float* __restrict__ Wa0,
                             const float* __restrict__ Wa1, const float* __restrict__ Wp0,
                             const float* __restrict__ Wp1, const float* __restrict__ Wp2,
                             u16* __restrict__ ws) {
  int idx = blockIdx.x * 256 + threadIdx.x;
  float v;
  if (idx < 8192) {
    int n = idx >> 7, k = idx & 127;
    v = (n < 50 && k < 100) ? Wc[k * 50 + n] : 0.f;
  } else if (idx < 24576) {
    int i = idx - 8192; int n = i >> 6, k = i & 63;
    v = (k < 50) ? Wa0[k * 256 + n] : 0.f;
  } else if (idx < 126976) {
    int i = idx - 24576; int n = i >> 8, k = i & 255;
    v = Wa1[k * 400 + n];
  } else if (idx < 233472) {
    int i = idx - 126976; int n = i / 416, k = i - n * 416;
    v = (k < 400) ? Wp0[k * 256 + n] : 0.f;
  } else if (idx < 299008) {
    int i = idx - 233472; int n = i >> 8, k = i & 255;
    v = Wp1[k * 256 + n];
  } else if (idx < 303104) {
    int i = idx - 299008; int n = i >> 8, k = i & 255;
    v = (n < 8) ? Wp2[k * 8 + n] : 0.f;
  } else {
    return;
  }
  ws[idx] = f2h(v);
}

// ---------------- fused actor ----------------
// R15: BISECTION round. R10-family (3 bundled changes) spills ~0.7-2.3 GB of
// scratch per launch regardless of staging placement (R13), unrolling, slot
// sequencing, or launch-bounds hints (R14) -- three mechanism theories
// falsified. R9 is the proven non-spilling anchor (285us, WRITE 9MB, FETCH
// 95MB). This round = EXACTLY R9's structure (in-loop staging, single sH,
// 2 barriers/obj, dual-slot a1 in one kb loop, LDS 54272,
// __launch_bounds__(1024)) + ONE change: operand-swapped MFMA with packed
// epilogues, targeting R9's measured 2.7e7 LDS bank-conflict cycles and
// scalar-u16 epilogue stores:
//   mfma(Wfrag, Xfrag) => acc[rg] = D[row=nl-ish][col = n0 + q*4 + rg]
//   -> all LDS epilogue stores become 8B v2u (4xfp16 consecutive cols),
//      biases become aligned v4f loads, final out store becomes v4f.
// If this round ALSO spills, the swapped-epilogue path is the proven trigger;
// if clean, bank the win and re-add R10's other changes one at a time.
//
// LDS map (54272 B static), phase ping-pong (same as R9):
//   sAtt [64][56]  @ 0      sG [64][136] @ 7168 (dead after cast)
//   sX   [64][72]  @ 7168   sH [64][264] @ 16384
//   sY   [64][424] @ 0      sP [64][264] @ 0
__global__ __launch_bounds__(1024) void actor_kernel(
    const float* __restrict__ o, const float* __restrict__ g,
    const float* __restrict__ b_cast, const float* __restrict__ b_a0,
    const float* __restrict__ b_a1, const float* __restrict__ b_p0,
    const float* __restrict__ b_p1, const float* __restrict__ b_p2,
    const u16* __restrict__ wsb, float* __restrict__ out) {
  __shared__ __align__(16) char smem[54272];
  u16* sAtt = (u16*)smem;            // [64][56]
  u16* sG   = (u16*)(smem + 7168);   // [64][136]
  u16* sX   = (u16*)(smem + 7168);   // [64][72]
  u16* sH   = (u16*)(smem + 16384);  // [64][264]
  u16* sY   = (u16*)smem;            // [64][424]
  u16* sP   = (u16*)smem;            // [64][264]

  const u16* WcT  = wsb;             // [64][128]
  const u16* Wa0T = wsb + 8192;      // [256][64]
  const u16* Wa1T = wsb + 24576;     // [400][256]
  const u16* Wp0T = wsb + 126976;    // [256][416]
  const u16* Wp1T = wsb + 233472;    // [256][256]
  const u16* Wp2T = wsb + 299008;    // [16][256]

  const int tid  = threadIdx.x;
  const int lane = tid & 63;
  const int w    = tid >> 6;   // wave 0..15
  const int nl   = lane & 15;  // MFMA 16-dim index
  const int q    = lane >> 4;  // quad
  const int row0 = blockIdx.x * 64;

  // ---- stage g -> sG (fp16, K zero-padded 100->128); NT: g is single-use ----
  for (int idx = tid; idx < 64 * 128; idx += 1024) {
    int r = idx >> 7, c = idx & 127;
    float v = (c < 100) ? __builtin_nontemporal_load(&g[(size_t)(row0 + r) * 100 + c]) : 0.f;
    sG[r * 136 + c] = f2h(v);
  }
  __syncthreads();

  // ---- attention = sigmoid(g @ W_cast + b_cast); 16 waves, 1 tile each ----
  {
    const int rb = w >> 2, nbq = w & 3;
    v4f acc = {};
#pragma unroll
    for (int kb = 0; kb < 4; ++kb) {
      v8h bh = *(const v8h*)(WcT + (nbq * 16 + nl) * 128 + kb * 32 + q * 8);
      v8h a  = *(const v8h*)&sG[(rb * 16 + nl) * 136 + kb * 32 + q * 8];
      acc = MFMA16(bh, a, acc);  // swapped: acc[rg] = D[rb*16+nl][nbq*16+q*4+rg]
    }
    const int row = rb * 16 + nl;
#pragma unroll
    for (int rg = 0; rg < 4; ++rg) {
      int col = nbq * 16 + q * 4 + rg;
      if (col < 50) {
        float v = acc[rg] + b_cast[col];
        v = 1.f / (1.f + __expf(-v));
        sAtt[row * 56 + col] = f2h(v);
      }
    }
  }
  __syncthreads();  // sAtt visible; sG dead

  // ---- x body part (cols 0..19) + zero pad (cols 50..63); NT o loads ----
  for (int idx = tid; idx < 64 * 20; idx += 1024) {
    int r = idx / 20, c = idx - r * 20;
    int src = (c < 10) ? c : (c + 120);
    float v = __builtin_nontemporal_load(&o[(size_t)(row0 + r) * 260 + src]) * h2f(sAtt[r * 56 + c]);
    sX[r * 72 + c] = f2h(v);
  }
  for (int idx = tid; idx < 64 * 14; idx += 1024) {
    int r = idx / 14, c = idx - r * 14;
    sX[r * 72 + 50 + c] = 0;
  }

  // ---- persistent per-wave state for a1 (y accumulator in registers) ----
  const int  nb0  = w;              // y N-tile 0..15
  const int  nb1  = w + 16;         // y N-tile 16..24 (w < 9)
  const bool has1 = (nb1 < 25);     // wave-uniform
  v4f y0[4] = {};  // persistent across object loop
  v4f y1[4] = {};  // (only meaningful for w < 9)

  // ---- object loop (R9 structure: stage obj x; B; a0; B; a1) ----
  for (int obj = 0; obj < 8; ++obj) {
    // object part of x (cols 20..49); NT o loads
    for (int idx = tid; idx < 64 * 30; idx += 1024) {
      int r = idx / 30, j = idx - r * 30;
      int src = (j < 15) ? (10 + 15 * obj + j) : (125 + 15 * obj + j);
      float v = __builtin_nontemporal_load(&o[(size_t)(row0 + r) * 260 + src]) * h2f(sAtt[r * 56 + 20 + j]);
      sX[r * 72 + 20 + j] = f2h(v);
    }
    __syncthreads();  // sX ready; also guarantees prev-obj a1 sH reads done

    // h = relu(x @ W_a0 + b_a0)  (K=64, N=256; wave owns n-tile w)
    {
      v4f acc[4] = {};
#pragma unroll
      for (int kb = 0; kb < 2; ++kb) {
        v8h b0 = *(const v8h*)(Wa0T + (w * 16 + nl) * 64 + kb * 32 + q * 8);
#pragma unroll
        for (int rb = 0; rb < 4; ++rb) {
          v8h a = *(const v8h*)&sX[(rb * 16 + nl) * 72 + kb * 32 + q * 8];
          acc[rb] = MFMA16(b0, a, acc[rb]);  // D[rb*16+nl][w*16+q*4+rg]
        }
      }
      v4f bs = *(const v4f*)&b_a0[w * 16 + q * 4];
#pragma unroll
      for (int rb = 0; rb < 4; ++rb) {
        float v0 = acc[rb][0] + bs[0]; v0 = v0 > 0.f ? v0 : 0.f;
        float v1 = acc[rb][1] + bs[1]; v1 = v1 > 0.f ? v1 : 0.f;
        float v2 = acc[rb][2] + bs[2]; v2 = v2 > 0.f ? v2 : 0.f;
        float v3 = acc[rb][3] + bs[3]; v3 = v3 > 0.f ? v3 : 0.f;
        v2u pk; pk[0] = pk2(v0, v1); pk[1] = pk2(v2, v3);
        *(v2u*)&sH[(rb * 16 + nl) * 264 + w * 16 + q * 4] = pk;
      }
    }
    __syncthreads();  // sH ready; all sX reads done

    // y += relu(h @ W_a1 + b_a1)  (K=256, N=400; wave owns nb0 [+ nb1];
    // dual-slot in one kb loop, A-fragments shared -- exactly R9's shape)
    {
      v4f t0[4] = {}, t1[4] = {};
#pragma unroll
      for (int kb = 0; kb < 8; ++kb) {
        v8h b0 = *(const v8h*)(Wa1T + (nb0 * 16 + nl) * 256 + kb * 32 + q * 8);
        v8h b1;
        if (has1) b1 = *(const v8h*)(Wa1T + (nb1 * 16 + nl) * 256 + kb * 32 + q * 8);
#pragma unroll
        for (int rb = 0; rb < 4; ++rb) {
          v8h a = *(const v8h*)&sH[(rb * 16 + nl) * 264 + kb * 32 + q * 8];
          t0[rb] = MFMA16(b0, a, t0[rb]);
          if (has1) t1[rb] = MFMA16(b1, a, t1[rb]);
        }
      }
      v4f bs0 = *(const v4f*)&b_a1[nb0 * 16 + q * 4];
#pragma unroll
      for (int rb = 0; rb < 4; ++rb)
#pragma unroll
        for (int rg = 0; rg < 4; ++rg) {
          float v = t0[rb][rg] + bs0[rg];
          y0[rb][rg] += (v > 0.f ? v : 0.f);
        }
      if (has1) {
        v4f bs1 = *(const v4f*)&b_a1[nb1 * 16 + q * 4];
#pragma unroll
        for (int rb = 0; rb < 4; ++rb)
#pragma unroll
          for (int rg = 0; rg < 4; ++rg) {
            float v = t1[rb][rg] + bs1[rg];
            y1[rb][rg] += (v > 0.f ? v : 0.f);
          }
      }
    }
    // no barrier: next x-write touches only sX (a1 read sH/global + own regs)
  }
  __syncthreads();  // all a1 reads/writes done; region A becomes sY

  // ---- write y regs -> sY (fp16, [64][424], K padded 400->416) ----
  if (tid < 512) {  // pad cols 400..415
    int r = tid >> 3, uu = tid & 7;
    *(u32*)&sY[r * 424 + 400 + 2 * uu] = 0;
  }
#pragma unroll
  for (int rb = 0; rb < 4; ++rb) {
    const int row = rb * 16 + nl;
    v2u pk0; pk0[0] = pk2(y0[rb][0], y0[rb][1]); pk0[1] = pk2(y0[rb][2], y0[rb][3]);
    *(v2u*)&sY[row * 424 + nb0 * 16 + q * 4] = pk0;
    if (has1) {
      v2u pk1; pk1[0] = pk2(y1[rb][0], y1[rb][1]); pk1[1] = pk2(y1[rb][2], y1[rb][3]);
      *(v2u*)&sY[row * 424 + nb1 * 16 + q * 4] = pk1;
    }
  }
  __syncthreads();  // sY visible

  // ---- p0 = relu(y @ W_p0 + b_p0)  (K=416, N=256; wave owns n-tile w) ----
  v4f p0acc[4] = {};
#pragma unroll
  for (int kb = 0; kb < 13; ++kb) {
    v8h b0 = *(const v8h*)(Wp0T + (w * 16 + nl) * 416 + kb * 32 + q * 8);
#pragma unroll
    for (int rb = 0; rb < 4; ++rb) {
      v8h a = *(const v8h*)&sY[(rb * 16 + nl) * 424 + kb * 32 + q * 8];
      p0acc[rb] = MFMA16(b0, a, p0acc[rb]);
    }
  }
  __syncthreads();  // all sY reads done; region becomes sP
  {
    v4f bs = *(const v4f*)&b_p0[w * 16 + q * 4];
#pragma unroll
    for (int rb = 0; rb < 4; ++rb) {
      float v0 = p0acc[rb][0] + bs[0]; v0 = v0 > 0.f ? v0 : 0.f;
      float v1 = p0acc[rb][1] + bs[1]; v1 = v1 > 0.f ? v1 : 0.f;
      float v2 = p0acc[rb][2] + bs[2]; v2 = v2 > 0.f ? v2 : 0.f;
      float v3 = p0acc[rb][3] + bs[3]; v3 = v3 > 0.f ? v3 : 0.f;
      v2u pk; pk[0] = pk2(v0, v1); pk[1] = pk2(v2, v3);
      *(v2u*)&sP[(rb * 16 + nl) * 264 + w * 16 + q * 4] = pk;
    }
  }
  __syncthreads();  // sP visible

  // ---- p1 = relu(p0 @ W_p1 + b_p1)  (K=256, N=256; in-place rewrite) ----
  v4f p1acc[4] = {};
#pragma unroll
  for (int kb = 0; kb < 8; ++kb) {
    v8h b0 = *(const v8h*)(Wp1T + (w * 16 + nl) * 256 + kb * 32 + q * 8);
#pragma unroll
    for (int rb = 0; rb < 4; ++rb) {
      v8h a = *(const v8h*)&sP[(rb * 16 + nl) * 264 + kb * 32 + q * 8];
      p1acc[rb] = MFMA16(b0, a, p1acc[rb]);
    }
  }
  __syncthreads();  // all sP reads done
  {
    v4f bs = *(const v4f*)&b_p1[w * 16 + q * 4];
#pragma unroll
    for (int rb = 0; rb < 4; ++rb) {
      float v0 = p1acc[rb][0] + bs[0]; v0 = v0 > 0.f ? v0 : 0.f;
      float v1 = p1acc[rb][1] + bs[1]; v1 = v1 > 0.f ? v1 : 0.f;
      float v2 = p1acc[rb][2] + bs[2]; v2 = v2 > 0.f ? v2 : 0.f;
      float v3 = p1acc[rb][3] + bs[3]; v3 = v3 > 0.f ? v3 : 0.f;
      v2u pk; pk[0] = pk2(v0, v1); pk[1] = pk2(v2, v3);
      *(v2u*)&sP[(rb * 16 + nl) * 264 + w * 16 + q * 4] = pk;
    }
  }
  __syncthreads();  // sP(p1) visible

  // ---- out = tanh(p1 @ W_p2 + b_p2)  (K=256, N=8; waves 0..3 own rows) ----
  if (w < 4) {
    v4f acc = {};
#pragma unroll
    for (int kb = 0; kb < 8; ++kb) {
      v8h a = *(const v8h*)&sP[(w * 16 + nl) * 264 + kb * 32 + q * 8];
      v8h b = *(const v8h*)(Wp2T + nl * 256 + kb * 32 + q * 8);
      acc = MFMA16(b, a, acc);  // acc[rg] = OUT[w*16+nl][q*4+rg]
    }
    if (q < 2) {
      v4f bp = *(const v4f*)&b_p2[q * 4];
      v4f r;
#pragma unroll
      for (int rg = 0; rg < 4; ++rg) r[rg] = tanhf(acc[rg] + bp[rg]);
      *(v4f*)&out[(size_t)(row0 + w * 16 + nl) * 8 + q * 4] = r;
    }
  }
}

extern "C" void kernel_launch(void* const* d_in, const int* in_sizes, int n_in,
                              void* d_out, int out_size, void* d_ws, size_t ws_size,
                              hipStream_t stream) {
  const float* o   = (const float*)d_in[0];
  const float* g   = (const float*)d_in[1];
  const float* Wc  = (const float*)d_in[2];
  const float* bc  = (const float*)d_in[3];
  const float* Wa0 = (const float*)d_in[4];
  const float* ba0 = (const float*)d_in[5];
  const float* Wa1 = (const float*)d_in[6];
  const float* ba1 = (const float*)d_in[7];
  const float* Wp0 = (const float*)d_in[8];
  const float* bp0 = (const float*)d_in[9];
  const float* Wp1 = (const float*)d_in[10];
  const float* bp1 = (const float*)d_in[11];
  const float* Wp2 = (const float*)d_in[12];
  const float* bp2 = (const float*)d_in[13];
  u16* ws = (u16*)d_ws;
  float* out = (float*)d_out;

  int rows = in_sizes[0] / 260;  // 65536

  prep_weights<<<1184, 256, 0, stream>>>(Wc, Wa0, Wa1, Wp0, Wp1, Wp2, ws);
  actor_kernel<<<rows / 64, 1024, 0, stream>>>(o, g, bc, ba0, ba1, bp0, bp1, bp2, ws, out);
}

// Round 8
// 348.052 us; speedup vs baseline: 3.1594x; 3.1594x over previous
//
#include <hip/hip_runtime.h>
#include <hip/hip_bf16.h>

typedef _Float16 f16;
typedef f16 v8h __attribute__((ext_vector_type(8)));
typedef float v4f __attribute__((ext_vector_type(4)));
typedef float v2f __attribute__((ext_vector_type(2)));
typedef unsigned short u16;
typedef unsigned int u32;

__device__ __forceinline__ u16 f2h(float f) {
  f16 h = (f16)f;
  return __builtin_bit_cast(unsigned short, h);
}
__device__ __forceinline__ float h2f(u16 u) {
  f16 h = __builtin_bit_cast(f16, u);
  return (float)h;
}
#define MFMA16(a, b, c) __builtin_amdgcn_mfma_f32_16x16x32_f16((a), (b), (c), 0, 0, 0)

// ---------------- weight prep: fp32 row-major -> fp16 transposed/padded ----------------
// ws layout (u16 element offsets):
//   WcT  [64][128]  @ 0        (from W_cast 100x50,  zero-pad n>=50, k>=100)
//   Wa0T [256][64]  @ 8192     (from W_a0  50x256,   zero-pad k>=50)
//   Wa1T [400][256] @ 24576    (from W_a1  256x400)
//   Wp0T [256][416] @ 126976   (from W_p0  400x256,  zero-pad k>=400)
//   Wp1T [256][256] @ 233472   (from W_p1  256x256)
//   Wp2T [16][256]  @ 299008   (from W_p2  256x8,    zero-pad n>=8)
__global__ void prep_weights(const float* __restrict__ Wc, const float* __restrict__ Wa0,
                             const float* __restrict__ Wa1, const float* __restrict__ Wp0,
                             const float* __restrict__ Wp1, const float* __restrict__ Wp2,
                             u16* __restrict__ ws) {
  int idx = blockIdx.x * 256 + threadIdx.x;
  float v;
  if (idx < 8192) {
    int n = idx >> 7, k = idx & 127;
    v = (n < 50 && k < 100) ? Wc[k * 50 + n] : 0.f;
  } else if (idx < 24576) {
    int i = idx - 8192; int n = i >> 6, k = i & 63;
    v = (k < 50) ? Wa0[k * 256 + n] : 0.f;
  } else if (idx < 126976) {
    int i = idx - 24576; int n = i >> 8, k = i & 255;
    v = Wa1[k * 400 + n];
  } else if (idx < 233472) {
    int i = idx - 126976; int n = i / 416, k = i - n * 416;
    v = (k < 400) ? Wp0[k * 256 + n] : 0.f;
  } else if (idx < 299008) {
    int i = idx - 233472; int n = i >> 8, k = i & 255;
    v = Wp1[k * 256 + n];
  } else if (idx < 303104) {
    int i = idx - 299008; int n = i >> 8, k = i & 255;
    v = (n < 8) ? Wp2[k * 8 + n] : 0.f;
  } else {
    return;
  }
  ws[idx] = f2h(v);
}

// ---------------- fused actor ----------------
// R16: bisection continues. Known: R9 (in-loop staging, single sH, unswapped
// MFMA, scalar epilogues) = 285us, NO spill. R15 proved swap+packed-epilogue
// ALONE triggers the spill (the kernel sits exactly at the 128 unified
// regs/wave cliff: 64 arch VGPR + 64 AGPR for y/t accumulators; 1024 threads
// -> 4 waves/SIMD hard -> any extra epilogue temporaries spill y0/y1).
// R16 tests the OTHER two R10 changes in isolation, both register-neutral in
// the a1 phase:
//   1. x staged ONCE into sXall[8][64][72] before the loop (loads/VALU leave
//      the serial per-object chain; no persistent regs -- y0/y1 not yet live).
//   2. sH double-buffered -> 1 barrier per object (parity select is a
//      wave-uniform SGPR op).
// MFMA operand order, all epilogues, biases: EXACTLY R9 (scalar, unswapped).
// Verdict counter: WRITE_SIZE. ~9 MB = clean; >100 MB = spill -> R17 reverts
// to exact R9.
//
// LDS map (148480 B static):
//   sAtt [64][56]       @ 0       (7168)
//   sG   [64][136]      @ 7168    (17408, dead after cast)
//   sXall[8][64][72]    @ 7168    (73728) -> end 80896
//   sH0  [64][264]      @ 80896   (33792)
//   sH1  [64][264]      @ 114688  (33792) -> end 148480
//   sY   [64][424]      @ 7168    (54272, after obj loop; sXall dead)
//   sP   [64][264]      @ 7168    (33792, after p0 reads sY)
__global__ __launch_bounds__(1024) void actor_kernel(
    const float* __restrict__ o, const float* __restrict__ g,
    const float* __restrict__ b_cast, const float* __restrict__ b_a0,
    const float* __restrict__ b_a1, const float* __restrict__ b_p0,
    const float* __restrict__ b_p1, const float* __restrict__ b_p2,
    const u16* __restrict__ wsb, float* __restrict__ out) {
  __shared__ __align__(16) char smem[148480];
  u16* sAtt = (u16*)smem;             // [64][56]
  u16* sG   = (u16*)(smem + 7168);    // [64][136]
  u16* sX0  = (u16*)(smem + 7168);    // [8][64][72]
  u16* sH0  = (u16*)(smem + 80896);   // [64][264]
  u16* sH1  = (u16*)(smem + 114688);  // [64][264]
  u16* sY   = (u16*)(smem + 7168);    // [64][424]
  u16* sP   = (u16*)(smem + 7168);    // [64][264]

  const u16* WcT  = wsb;             // [64][128]
  const u16* Wa0T = wsb + 8192;      // [256][64]
  const u16* Wa1T = wsb + 24576;     // [400][256]
  const u16* Wp0T = wsb + 126976;    // [256][416]
  const u16* Wp1T = wsb + 233472;    // [256][256]
  const u16* Wp2T = wsb + 299008;    // [16][256]

  const int tid  = threadIdx.x;
  const int lane = tid & 63;
  const int w    = tid >> 6;   // wave 0..15
  const int nl   = lane & 15;  // MFMA m/n index
  const int q    = lane >> 4;  // quad
  const int row0 = blockIdx.x * 64;

  // ---- stage g -> sG (fp16, K zero-padded 100->128); NT: g is single-use ----
  for (int idx = tid; idx < 64 * 128; idx += 1024) {
    int r = idx >> 7, c = idx & 127;
    float v = (c < 100) ? __builtin_nontemporal_load(&g[(size_t)(row0 + r) * 100 + c]) : 0.f;
    sG[r * 136 + c] = f2h(v);
  }
  __syncthreads();  // B1

  // ---- attention = sigmoid(g @ W_cast + b_cast); 16 waves, 1 tile each ----
  // (EXACT R9 form: unswapped MFMA, scalar epilogue)
  {
    const int rb = w >> 2, nbq = w & 3;
    const int col = nbq * 16 + nl;
    v4f acc = {};
#pragma unroll
    for (int kb = 0; kb < 4; ++kb) {
      v8h bh = *(const v8h*)(WcT + col * 128 + kb * 32 + q * 8);
      v8h a  = *(const v8h*)&sG[(rb * 16 + nl) * 136 + kb * 32 + q * 8];
      acc = MFMA16(a, bh, acc);
    }
    if (col < 50) {
      float bias = b_cast[col];
#pragma unroll
      for (int rg = 0; rg < 4; ++rg) {
        float v = acc[rg] + bias;
        v = 1.f / (1.f + __expf(-v));
        sAtt[(rb * 16 + q * 4 + rg) * 56 + col] = f2h(v);
      }
    }
  }
  __syncthreads();  // B2: sAtt visible; sG dead

  // ---- build sXall[8][64][72]: attenuated fp16 x for ALL objects ----
  // (loads placed here: short live ranges, before y0/y1 exist)
#pragma unroll
  for (int i = 0; i < 4; ++i) {
    int idx = tid + i * 1024;
    if (idx < 3840) {
      int r = idx / 60, c2 = idx - r * 60;
      const float* rp = o + (size_t)(row0 + r) * 260;
      v2f f1 = *(const v2f*)(rp + 10 + 2 * c2);   // cols 10..129
      v2f f2 = *(const v2f*)(rp + 140 + 2 * c2);  // cols 140..259
      int cc0 = 2 * c2, cc1 = cc0 + 1;
      int ob0 = cc0 / 15, j0 = cc0 - ob0 * 15;
      int ob1 = cc1 / 15, j1 = cc1 - ob1 * 15;
      u16* xr = sX0 + r * 72;
      xr[ob0 * 4608 + 20 + j0] = f2h(f1[0] * h2f(sAtt[r * 56 + 20 + j0]));
      xr[ob1 * 4608 + 20 + j1] = f2h(f1[1] * h2f(sAtt[r * 56 + 20 + j1]));
      xr[ob0 * 4608 + 35 + j0] = f2h(f2[0] * h2f(sAtt[r * 56 + 35 + j0]));
      xr[ob1 * 4608 + 35 + j1] = f2h(f2[1] * h2f(sAtt[r * 56 + 35 + j1]));
    }
  }
  if (tid < 640) {  // body part: 64 rows x 10 float2 (dest cols 0..19)
    int r = tid / 10, hh = tid - r * 10;
    const float* rp = o + (size_t)(row0 + r) * 260;
    int src = (hh < 5) ? (2 * hh) : (2 * hh + 120);
    v2f fb = *(const v2f*)(rp + src);
    int c0 = 2 * hh, c1 = c0 + 1;
    u16 x0 = f2h(fb[0] * h2f(sAtt[r * 56 + c0]));
    u16 x1 = f2h(fb[1] * h2f(sAtt[r * 56 + c1]));
    u16* xr = sX0 + r * 72;
#pragma unroll
    for (int ob = 0; ob < 8; ++ob) {
      xr[ob * 4608 + c0] = x0;
      xr[ob * 4608 + c1] = x1;
    }
  }
  // zero pad cols 50..63 for all objects (7 dword stores per (r,ob))
  for (int idx = tid; idx < 64 * 8 * 7; idx += 1024) {
    int t = idx; int uu = t % 7; t /= 7; int ob = t & 7; int r = t >> 3;
    *(u32*)&sX0[ob * 4608 + r * 72 + 50 + 2 * uu] = 0;
  }
  __syncthreads();  // B3: sXall ready

  // ---- persistent per-wave state for a1 (y accumulator in registers) ----
  const int  nb0  = w;              // y N-tile 0..15
  const int  nb1  = w + 16;         // y N-tile 16..24 (w < 9)
  const bool has1 = (nb1 < 25);     // wave-uniform
  v4f y0[4] = {};  // persistent across object loop
  v4f y1[4] = {};  // (only meaningful for w < 9)

  // ---- object loop: {a0 -> sHbuf[obj&1]; barrier; a1 -> y regs} ----
  // (EXACT R9 math/epilogues; only staging removed + sH dbuf'd)
  for (int obj = 0; obj < 8; ++obj) {
    u16* sHd = (obj & 1) ? sH1 : sH0;
    const u16* sXo = sX0 + obj * 4608;

    // h = relu(x @ W_a0 + b_a0)  (K=64, N=256; wave owns n-tile w)
    {
      v4f acc[4] = {};
#pragma unroll
      for (int kb = 0; kb < 2; ++kb) {
        v8h b0 = *(const v8h*)(Wa0T + (w * 16 + nl) * 64 + kb * 32 + q * 8);
#pragma unroll
        for (int rb = 0; rb < 4; ++rb) {
          v8h a = *(const v8h*)&sXo[(rb * 16 + nl) * 72 + kb * 32 + q * 8];
          acc[rb] = MFMA16(a, b0, acc[rb]);
        }
      }
      const int col = w * 16 + nl;
      float bias = b_a0[col];
#pragma unroll
      for (int rb = 0; rb < 4; ++rb)
#pragma unroll
        for (int rg = 0; rg < 4; ++rg) {
          float v = acc[rb][rg] + bias;
          v = v > 0.f ? v : 0.f;
          sHd[(rb * 16 + q * 4 + rg) * 264 + col] = f2h(v);
        }
    }
    __syncthreads();  // sH[obj&1] ready (1 barrier per object)

    // y += relu(h @ W_a1 + b_a1)  (K=256, N=400; wave owns nb0 [+ nb1];
    // dual-slot in one kb loop, A-fragments shared -- exactly R9's shape)
    {
      v4f t0[4] = {}, t1[4] = {};
#pragma unroll
      for (int kb = 0; kb < 8; ++kb) {
        v8h b0 = *(const v8h*)(Wa1T + (nb0 * 16 + nl) * 256 + kb * 32 + q * 8);
        v8h b1;
        if (has1) b1 = *(const v8h*)(Wa1T + (nb1 * 16 + nl) * 256 + kb * 32 + q * 8);
#pragma unroll
        for (int rb = 0; rb < 4; ++rb) {
          v8h a = *(const v8h*)&sHd[(rb * 16 + nl) * 264 + kb * 32 + q * 8];
          t0[rb] = MFMA16(a, b0, t0[rb]);
          if (has1) t1[rb] = MFMA16(a, b1, t1[rb]);
        }
      }
      float bias0 = b_a1[nb0 * 16 + nl];
#pragma unroll
      for (int rb = 0; rb < 4; ++rb)
#pragma unroll
        for (int rg = 0; rg < 4; ++rg) {
          float v = t0[rb][rg] + bias0;
          y0[rb][rg] += (v > 0.f ? v : 0.f);
        }
      if (has1) {
        float bias1 = b_a1[nb1 * 16 + nl];
#pragma unroll
        for (int rb = 0; rb < 4; ++rb)
#pragma unroll
          for (int rg = 0; rg < 4; ++rg) {
            float v = t1[rb][rg] + bias1;
            y1[rb][rg] += (v > 0.f ? v : 0.f);
          }
      }
    }
    // no barrier: a0(obj+1) writes the OTHER sH buffer; sXall is read-only;
    // sH buffer reuse (obj+2) is dominated by the next iteration's barrier.
  }
  __syncthreads();  // all a1 reads done; sXall region becomes sY

  // ---- write y regs -> sY (fp16, [64][424], K padded 400->416) ----
  // (EXACT R9 form: scalar u16 stores)
  for (int idx = tid; idx < 64 * 16; idx += 1024) {
    int r = idx >> 4, c = idx & 15;
    sY[r * 424 + 400 + c] = 0;
  }
#pragma unroll
  for (int rb = 0; rb < 4; ++rb)
#pragma unroll
    for (int rg = 0; rg < 4; ++rg) {
      const int row = rb * 16 + q * 4 + rg;
      sY[row * 424 + nb0 * 16 + nl] = f2h(y0[rb][rg]);
      if (has1) sY[row * 424 + nb1 * 16 + nl] = f2h(y1[rb][rg]);
    }
  __syncthreads();  // sY visible

  // ---- p0 = relu(y @ W_p0 + b_p0)  (K=416, N=256; wave owns n-tile w) ----
  v4f p0acc[4] = {};
#pragma unroll
  for (int kb = 0; kb < 13; ++kb) {
    v8h b0 = *(const v8h*)(Wp0T + (w * 16 + nl) * 416 + kb * 32 + q * 8);
#pragma unroll
    for (int rb = 0; rb < 4; ++rb) {
      v8h a = *(const v8h*)&sY[(rb * 16 + nl) * 424 + kb * 32 + q * 8];
      p0acc[rb] = MFMA16(a, b0, p0acc[rb]);
    }
  }
  __syncthreads();  // all sY reads done; region becomes sP
  {
    const int col = w * 16 + nl;
    float bias = b_p0[col];
#pragma unroll
    for (int rb = 0; rb < 4; ++rb)
#pragma unroll
      for (int rg = 0; rg < 4; ++rg) {
        float v = p0acc[rb][rg] + bias;
        v = v > 0.f ? v : 0.f;
        sP[(rb * 16 + q * 4 + rg) * 264 + col] = f2h(v);
      }
  }
  __syncthreads();  // sP visible

  // ---- p1 = relu(p0 @ W_p1 + b_p1)  (K=256, N=256; in-place rewrite) ----
  v4f p1acc[4] = {};
#pragma unroll
  for (int kb = 0; kb < 8; ++kb) {
    v8h b0 = *(const v8h*)(Wp1T + (w * 16 + nl) * 256 + kb * 32 + q * 8);
#pragma unroll
    for (int rb = 0; rb < 4; ++rb) {
      v8h a = *(const v8h*)&sP[(rb * 16 + nl) * 264 + kb * 32 + q * 8];
      p1acc[rb] = MFMA16(a, b0, p1acc[rb]);
    }
  }
  __syncthreads();  // all sP reads done
  {
    const int col = w * 16 + nl;
    float bias = b_p1[col];
#pragma unroll
    for (int rb = 0; rb < 4; ++rb)
#pragma unroll
      for (int rg = 0; rg < 4; ++rg) {
        float v = p1acc[rb][rg] + bias;
        v = v > 0.f ? v : 0.f;
        sP[(rb * 16 + q * 4 + rg) * 264 + col] = f2h(v);
      }
  }
  __syncthreads();  // sP(p1) visible

  // ---- out = tanh(p1 @ W_p2 + b_p2)  (K=256, N=8; waves 0..3 own rows) ----
  if (w < 4) {
    v4f acc = {};
#pragma unroll
    for (int kb = 0; kb < 8; ++kb) {
      v8h a = *(const v8h*)&sP[(w * 16 + nl) * 264 + kb * 32 + q * 8];
      v8h b = *(const v8h*)(Wp2T + nl * 256 + kb * 32 + q * 8);
      acc = MFMA16(a, b, acc);
    }
    if (nl < 8) {
      float bias = b_p2[nl];
#pragma unroll
      for (int rg = 0; rg < 4; ++rg)
        __builtin_nontemporal_store(tanhf(acc[rg] + bias),
                                    &out[(size_t)(row0 + w * 16 + q * 4 + rg) * 8 + nl]);
    }
  }
}

extern "C" void kernel_launch(void* const* d_in, const int* in_sizes, int n_in,
                              void* d_out, int out_size, void* d_ws, size_t ws_size,
                              hipStream_t stream) {
  const float* o   = (const float*)d_in[0];
  const float* g   = (const float*)d_in[1];
  const float* Wc  = (const float*)d_in[2];
  const float* bc  = (const float*)d_in[3];
  const float* Wa0 = (const float*)d_in[4];
  const float* ba0 = (const float*)d_in[5];
  const float* Wa1 = (const float*)d_in[6];
  const float* ba1 = (const float*)d_in[7];
  const float* Wp0 = (const float*)d_in[8];
  const float* bp0 = (const float*)d_in[9];
  const float* Wp1 = (const float*)d_in[10];
  const float* bp1 = (const float*)d_in[11];
  const float* Wp2 = (const float*)d_in[12];
  const float* bp2 = (const float*)d_in[13];
  u16* ws = (u16*)d_ws;
  float* out = (float*)d_out;

  int rows = in_sizes[0] / 260;  // 65536

  prep_weights<<<1184, 256, 0, stream>>>(Wc, Wa0, Wa1, Wp0, Wp1, Wp2, ws);
  actor_kernel<<<rows / 64, 1024, 0, stream>>>(o, g, bc, ba0, ba1, bp0, bp1, bp2, ws, out);
}